// Round 2
// baseline (95.837 us; speedup 1.0000x reference)
//
#include <hip/hip_runtime.h>

#define NC 5
#define NB 2
#define SPATIAL (128*128*128)
#define NVEC (SPATIAL/4)
#define SMOOTHF 1e-5f
#define NREP 32           // accumulator replicas (31 floats each, padded to 32)
#define GRIDX 1024        // 1024 x 2 blocks x 256 thr -> exactly 2 iters/thread
#define ITERS (NVEC / (GRIDX * 256))

// ws float layout: [0 .. NREP*32)   replicated accumulators
//                  [NREP*32]        int flag: target-is-int64

__global__ __launch_bounds__(1024) void init_and_detect(
    const unsigned long long* __restrict__ t, float* __restrict__ acc) {
    acc[threadIdx.x] = 0.f;                 // zero all 1024 replica slots
    if (threadIdx.x == 0) {
        int is64 = 1;
        for (int i = 0; i < 64; ++i)
            if (t[i] >= 5ull) { is64 = 0; break; }
        ((int*)acc)[NREP * 32] = is64;      // P(false pos | int32 data) ~ (1/5)^64
    }
}

__global__ __launch_bounds__(256, 8) void dpdc_main(
    const float* __restrict__ net, const void* __restrict__ targ,
    const float* __restrict__ dist, float* __restrict__ acc)
{
    const int b = blockIdx.y;
    const int t64 = ((const int*)acc)[NREP * 32];
    const float4* nb = (const float4*)(net + (size_t)b * NC * SPATIAL);
    const float4* db = (const float4*)(dist + (size_t)b * SPATIAL);
    const int4* t32p = (const int4*)((const int*)targ + (size_t)b * SPATIAL);
    const ulonglong2* t64p =
        (const ulonglong2*)((const unsigned long long*)targ + (size_t)b * SPATIAL);

    float tp[NC] = {0,0,0,0,0}, sp[NC] = {0,0,0,0,0}, cnt[NC] = {0,0,0,0,0};
    float nll = 0.f;

    int i = blockIdx.x * blockDim.x + threadIdx.x;
    const int stride = GRIDX * 256;
    #pragma unroll
    for (int it = 0; it < ITERS; ++it, i += stride) {
        float4 l[NC];
        #pragma unroll
        for (int c = 0; c < NC; ++c) l[c] = nb[(size_t)c * NVEC + i];
        float4 dd = db[i];
        int tt[4];
        if (t64) {
            ulonglong2 a = t64p[2 * i];
            ulonglong2 bq = t64p[2 * i + 1];
            tt[0] = (int)a.x; tt[1] = (int)a.y;
            tt[2] = (int)bq.x; tt[3] = (int)bq.y;
        } else {
            int4 a = t32p[i];
            tt[0] = a.x; tt[1] = a.y; tt[2] = a.z; tt[3] = a.w;
        }
        const float* dv = (const float*)&dd;
        #pragma unroll
        for (int j = 0; j < 4; ++j) {
            float lc[NC];
            #pragma unroll
            for (int c = 0; c < NC; ++c) lc[c] = ((const float*)&l[c])[j];
            float m = fmaxf(fmaxf(fmaxf(lc[0], lc[1]), fmaxf(lc[2], lc[3])), lc[4]);
            float e[NC];
            float s = 0.f;
            #pragma unroll
            for (int c = 0; c < NC; ++c) { e[c] = __expf(lc[c] - m); s += e[c]; }
            float inv = 1.0f / s;
            int t = tt[j];
            float lsel = lc[4];
            #pragma unroll
            for (int c = 0; c < 4; ++c) lsel = (t == c) ? lc[c] : lsel;
            float pd = dv[j] * inv;  // dist / sumexp
            #pragma unroll
            for (int c = 0; c < NC; ++c) {
                float p = e[c] * inv;
                sp[c] += p;
                tp[c] += (t == c) ? e[c] * pd : 0.f;
                cnt[c] += (t == c) ? 1.f : 0.f;
            }
            nll += __logf(s) - (lsel - m);
        }
    }

    // block reduction of 16 scalars: tp[5], sp[5], cnt[5], nll
    __shared__ float red[4][16];
    float vals[16];
    #pragma unroll
    for (int c = 0; c < NC; ++c) {
        vals[c] = tp[c]; vals[5 + c] = sp[c]; vals[10 + c] = cnt[c];
    }
    vals[15] = nll;
    const int lane = threadIdx.x & 63;
    const int wave = threadIdx.x >> 6;
    #pragma unroll
    for (int k = 0; k < 16; ++k) {
        float v = vals[k];
        #pragma unroll
        for (int off = 32; off > 0; off >>= 1) v += __shfl_down(v, off, 64);
        if (lane == 0) red[wave][k] = v;
    }
    __syncthreads();
    if (threadIdx.x < 16) {
        int k = threadIdx.x;
        float v = red[0][k] + red[1][k] + red[2][k] + red[3][k];
        float* racc = acc + (blockIdx.x & (NREP - 1)) * 32;
        float* dst;
        if (k < 5)       dst = &racc[b * NC + k];
        else if (k < 10) dst = &racc[10 + b * NC + (k - 5)];
        else if (k < 15) dst = &racc[20 + b * NC + (k - 10)];
        else             dst = &racc[30];
        atomicAdd(dst, v);
    }
}

__global__ __launch_bounds__(64) void finalize(const float* __restrict__ acc,
                                               float* __restrict__ out) {
    __shared__ float red[31];
    int j = threadIdx.x;
    if (j < 31) {
        float s = 0.f;
        for (int r = 0; r < NREP; ++r) s += acc[r * 32 + j];
        red[j] = s;
    }
    __syncthreads();
    if (j == 0) {
        float dcsum = 0.f;
        for (int b = 0; b < NB; ++b)
            for (int c = 0; c < NC; ++c) {
                float tpv = red[b * NC + c];
                float spv = red[10 + b * NC + c];
                float cv  = red[20 + b * NC + c];
                dcsum += (2.f * tpv + SMOOTHF) / (spv + cv + SMOOTHF);
            }
        float ce = red[30] / (float)((size_t)NB * SPATIAL);
        out[0] = ce - dcsum / (float)(NB * NC);
    }
}

extern "C" void kernel_launch(void* const* d_in, const int* in_sizes, int n_in,
                              void* d_out, int out_size, void* d_ws, size_t ws_size,
                              hipStream_t stream) {
    const float* net  = (const float*)d_in[0];
    const void*  targ = d_in[1];
    const float* dist = (const float*)d_in[2];
    float* acc = (float*)d_ws;

    init_and_detect<<<1, 1024, 0, stream>>>(
        (const unsigned long long*)targ, acc);
    dim3 grid(GRIDX, NB);
    dpdc_main<<<grid, 256, 0, stream>>>(net, targ, dist, acc);
    finalize<<<1, 64, 0, stream>>>(acc, (float*)d_out);
}

// Round 3
// 37.254 us; speedup vs baseline: 2.5725x; 2.5725x over previous
//
#include <hip/hip_runtime.h>

#define NC 5
#define NB 2
#define SPATIAL (128*128*128)
#define NVEC (SPATIAL/4)
#define SMOOTHF 1e-5f
#define NREP 32           // accumulator replicas (31 floats each, padded to 32)
#define GRIDX 1024        // 1024 x 2 blocks x 256 thr -> exactly 2 iters/thread
#define ITERS (NVEC / (GRIDX * 256))

// ws float layout: [0 .. NREP*32)   replicated accumulators
//                  [NREP*32]        int flag: target-is-int64

__global__ __launch_bounds__(1024) void init_and_detect(
    const unsigned long long* __restrict__ t, float* __restrict__ acc) {
    acc[threadIdx.x] = 0.f;                 // zero all 1024 replica slots
    if (threadIdx.x == 0) {
        int is64 = 1;
        for (int i = 0; i < 64; ++i)
            if (t[i] >= 5ull) { is64 = 0; break; }
        ((int*)acc)[NREP * 32] = is64;      // P(false pos | int32 data) ~ (1/5)^64
    }
}

// NOTE: no min-waves arg — round 2 showed __launch_bounds__(256,8) forces
// VGPR<=32 and 160 MB of scratch spill. Natural allocation is ~44 VGPR,
// which already permits 8 waves/SIMD (<64 VGPR threshold).
__global__ __launch_bounds__(256) void dpdc_main(
    const float* __restrict__ net, const void* __restrict__ targ,
    const float* __restrict__ dist, float* __restrict__ acc)
{
    const int b = blockIdx.y;
    const int t64 = ((const int*)acc)[NREP * 32];
    const float4* nb = (const float4*)(net + (size_t)b * NC * SPATIAL);
    const float4* db = (const float4*)(dist + (size_t)b * SPATIAL);
    const int4* t32p = (const int4*)((const int*)targ + (size_t)b * SPATIAL);
    const ulonglong2* t64p =
        (const ulonglong2*)((const unsigned long long*)targ + (size_t)b * SPATIAL);

    float tp[NC] = {0,0,0,0,0}, sp[NC] = {0,0,0,0,0}, cnt[NC] = {0,0,0,0,0};
    float nll = 0.f;

    int i = blockIdx.x * blockDim.x + threadIdx.x;
    const int stride = GRIDX * 256;
    #pragma unroll
    for (int it = 0; it < ITERS; ++it, i += stride) {
        float4 l[NC];
        #pragma unroll
        for (int c = 0; c < NC; ++c) l[c] = nb[(size_t)c * NVEC + i];
        float4 dd = db[i];
        int tt[4];
        if (t64) {
            ulonglong2 a = t64p[2 * i];
            ulonglong2 bq = t64p[2 * i + 1];
            tt[0] = (int)a.x; tt[1] = (int)a.y;
            tt[2] = (int)bq.x; tt[3] = (int)bq.y;
        } else {
            int4 a = t32p[i];
            tt[0] = a.x; tt[1] = a.y; tt[2] = a.z; tt[3] = a.w;
        }
        const float* dv = (const float*)&dd;
        #pragma unroll
        for (int j = 0; j < 4; ++j) {
            float lc[NC];
            #pragma unroll
            for (int c = 0; c < NC; ++c) lc[c] = ((const float*)&l[c])[j];
            float m = fmaxf(fmaxf(fmaxf(lc[0], lc[1]), fmaxf(lc[2], lc[3])), lc[4]);
            float e[NC];
            float s = 0.f;
            #pragma unroll
            for (int c = 0; c < NC; ++c) { e[c] = __expf(lc[c] - m); s += e[c]; }
            float inv = 1.0f / s;
            int t = tt[j];
            float lsel = lc[4];
            #pragma unroll
            for (int c = 0; c < 4; ++c) lsel = (t == c) ? lc[c] : lsel;
            float pd = dv[j] * inv;  // dist / sumexp
            #pragma unroll
            for (int c = 0; c < NC; ++c) {
                float p = e[c] * inv;
                sp[c] += p;
                tp[c] += (t == c) ? e[c] * pd : 0.f;
                cnt[c] += (t == c) ? 1.f : 0.f;
            }
            nll += __logf(s) - (lsel - m);
        }
    }

    // block reduction of 16 scalars: tp[5], sp[5], cnt[5], nll
    __shared__ float red[4][16];
    float vals[16];
    #pragma unroll
    for (int c = 0; c < NC; ++c) {
        vals[c] = tp[c]; vals[5 + c] = sp[c]; vals[10 + c] = cnt[c];
    }
    vals[15] = nll;
    const int lane = threadIdx.x & 63;
    const int wave = threadIdx.x >> 6;
    #pragma unroll
    for (int k = 0; k < 16; ++k) {
        float v = vals[k];
        #pragma unroll
        for (int off = 32; off > 0; off >>= 1) v += __shfl_down(v, off, 64);
        if (lane == 0) red[wave][k] = v;
    }
    __syncthreads();
    if (threadIdx.x < 16) {
        int k = threadIdx.x;
        float v = red[0][k] + red[1][k] + red[2][k] + red[3][k];
        float* racc = acc + (blockIdx.x & (NREP - 1)) * 32;
        float* dst;
        if (k < 5)       dst = &racc[b * NC + k];
        else if (k < 10) dst = &racc[10 + b * NC + (k - 5)];
        else if (k < 15) dst = &racc[20 + b * NC + (k - 10)];
        else             dst = &racc[30];
        atomicAdd(dst, v);
    }
}

__global__ __launch_bounds__(64) void finalize(const float* __restrict__ acc,
                                               float* __restrict__ out) {
    __shared__ float red[31];
    int j = threadIdx.x;
    if (j < 31) {
        float s = 0.f;
        for (int r = 0; r < NREP; ++r) s += acc[r * 32 + j];
        red[j] = s;
    }
    __syncthreads();
    if (j == 0) {
        float dcsum = 0.f;
        for (int b = 0; b < NB; ++b)
            for (int c = 0; c < NC; ++c) {
                float tpv = red[b * NC + c];
                float spv = red[10 + b * NC + c];
                float cv  = red[20 + b * NC + c];
                dcsum += (2.f * tpv + SMOOTHF) / (spv + cv + SMOOTHF);
            }
        float ce = red[30] / (float)((size_t)NB * SPATIAL);
        out[0] = ce - dcsum / (float)(NB * NC);
    }
}

extern "C" void kernel_launch(void* const* d_in, const int* in_sizes, int n_in,
                              void* d_out, int out_size, void* d_ws, size_t ws_size,
                              hipStream_t stream) {
    const float* net  = (const float*)d_in[0];
    const void*  targ = d_in[1];
    const float* dist = (const float*)d_in[2];
    float* acc = (float*)d_ws;

    init_and_detect<<<1, 1024, 0, stream>>>(
        (const unsigned long long*)targ, acc);
    dim3 grid(GRIDX, NB);
    dpdc_main<<<grid, 256, 0, stream>>>(net, targ, dist, acc);
    finalize<<<1, 64, 0, stream>>>(acc, (float*)d_out);
}